// Round 1
// baseline (248.645 us; speedup 1.0000x reference)
//
#include <hip/hip_runtime.h>
#include <hip/hip_bf16.h>

// GraphConvolution: out = relu( (W@x + b) @ adj^T + x ), B=4096, C=256, N=25.
// R6: latency-attack version. R5 was serialization-bound (all pipes <25%):
// 8 waves/CU, 3 draining __syncthreads per batch, loads fully exposed.
// Changes:
//  - 512-thread blocks (8 waves, o-range 32/wave) -> 16 waves/CU (2 blocks),
//    af shrinks to af[8][2]=64 VGPRs so everything fits 128 regs.
//  - per-wave-owned xs rows / ys cols / outS slice / store slice: only ys
//    needs cross-wave barriers -> 2 barriers/iter, neither drains vmcnt
//    (raw s_barrier asm; lgkmcnt(0) only where LDS visibility is needed).
//  - x[b+1] prefetched into registers at iter top, scattered to LDS after
//    the GEMM: global-load latency hidden under agg+gemm.

#define BATCH 4096
#define C 256
#define N 25
#define NB 8
#define XSTR 28      // xs fp32 row stride (112 B, 16B-aligned rows)
#define YSTR 264     // ys bf16 row stride (528 B, 16B-aligned rows)

typedef __bf16 bf16x8 __attribute__((ext_vector_type(8)));
typedef float f32x4 __attribute__((ext_vector_type(4)));

// ---- prep: Wshuf[(T*8+kk)*64+lane] = MFMA A-fragment, o-tile T (o=T*16+l15) ----
__global__ void prep_kernel(const float* __restrict__ W, const float* __restrict__ adj,
                            bf16x8* __restrict__ Wshuf, float* __restrict__ adjS) {
    int i = blockIdx.x * 256 + threadIdx.x;       // 8192 = 128 frags x 64 lanes
    int f = i >> 6, l = i & 63;
    int T = f >> 3, kk = f & 7;
    int quad = l >> 4, l15 = l & 15;
    int o = T * 16 + l15;
    int cb = kk * 32 + quad * 8;
    bf16x8 v;
    #pragma unroll
    for (int j = 0; j < 8; ++j) v[j] = (__bf16)W[o * C + cb + j];
    Wshuf[i] = v;
    if (blockIdx.x == 0 && threadIdx.x < 32) {
        float s = 0.f;
        if (threadIdx.x < N)
            for (int n = 0; n < N; ++n) s += adj[threadIdx.x * N + n];
        adjS[threadIdx.x] = s;
    }
}

__global__ __launch_bounds__(512, 4) void gcn_kernel(
    const float* __restrict__ x, const float* __restrict__ adj,
    const float* __restrict__ bias, const float* __restrict__ adjSg,
    const bf16x8* __restrict__ Wshuf, float* __restrict__ out)
{
    __shared__ __align__(16) float  xs[C * XSTR];   // 28672 B fp32 x tile
    __shared__ __align__(16) __bf16 ys[32 * YSTR];  // 16896 B bf16 y tile
    __shared__ __align__(16) float  outS[C * N];    // 25600 B out staging
    __shared__ __align__(16) __bf16 adjbf[32 * 40]; //  2560 B zero-padded adj
    __shared__ float biasS[C];                      //  1024 B  (total 74752 B)

    const int tid = threadIdx.x;                   // 0..511
    const int wv = tid >> 6, lane = tid & 63;      // 8 waves
    const int quad = lane >> 4, l15 = lane & 15;
    const int o0 = wv * 32;                        // wave's o-range == c-range
    const int b0 = blockIdx.x * NB;

    // ---- one-time: adj staging, bias, pinned W fragments (64 VGPRs) ----
    for (int e = tid; e < N * N; e += 512) {
        int m = e / N, n = e - m * N;
        adjbf[m * 40 + n] = (__bf16)adj[e];
    }
    if (tid < N) {
        #pragma unroll
        for (int n = N; n < 32; ++n) adjbf[tid * 40 + n] = (__bf16)0.f;
    } else if (tid < 32) {
        #pragma unroll
        for (int n = 0; n < 32; ++n) adjbf[tid * 40 + n] = (__bf16)0.f;
    }
    if (tid < C) biasS[tid] = bias[tid];

    bf16x8 af[8][2];   // 64 VGPRs, coalesced 1KB loads
    #pragma unroll
    for (int kk = 0; kk < 8; ++kk)
        #pragma unroll
        for (int ot = 0; ot < 2; ++ot)
            af[kk][ot] = Wshuf[(((wv * 2 + ot) * 8 + kk) << 6) + lane];

    const float aS0 = adjSg[l15];
    const float aS1 = adjSg[16 + l15];

    __syncthreads();   // adjbf/biasS ready (full drain, once)

    const bf16x8 a0 = *(const bf16x8*)&adjbf[l15 * 40 + quad * 8];
    const bf16x8 a1 = *(const bf16x8*)&adjbf[(16 + l15) * 40 + quad * 8];

    // ---- prologue: stage batch b0, own rows only (float4 range [wv*200, +200)) ----
    {
        const float* xb = x + (size_t)b0 * (C * N);
        float4 r0[4];
        #pragma unroll
        for (int rr = 0; rr < 4; ++rr)
            if (rr < 3 || lane < 8) r0[rr] = ((const float4*)xb)[wv * 200 + rr * 64 + lane];
        #pragma unroll
        for (int rr = 0; rr < 4; ++rr)
            if (rr < 3 || lane < 8) {
                int e = (wv * 200 + rr * 64 + lane) * 4;
                int c = e / N, n = e - c * N;
                float fv[4] = {r0[rr].x, r0[rr].y, r0[rr].z, r0[rr].w};
                #pragma unroll
                for (int j = 0; j < 4; ++j) {
                    xs[c * XSTR + n] = fv[j];
                    ++n; if (n == N) { n = 0; ++c; }
                }
            }
    }

    #pragma unroll 1
    for (int bi = 0; bi < NB; ++bi) {
        float* outb = out + (size_t)(b0 + bi) * (C * N);

        // ---- issue prefetch of x[b+1] (consumed by scatter after the GEMM) ----
        float4 rn[4];
        const bool pf = (bi + 1 < NB);
        if (pf) {
            const float* xb = x + (size_t)(b0 + bi + 1) * (C * N);
            #pragma unroll
            for (int rr = 0; rr < 4; ++rr)
                if (rr < 3 || lane < 8) rn[rr] = ((const float4*)xb)[wv * 200 + rr * 64 + lane];
        }

        // ---- agg MFMA on own rows: y[m][c]=sum_n adj[m][n]*x[c][n], c in [o0,o0+32) ----
        #pragma unroll
        for (int ctl = 0; ctl < 2; ++ctl) {
            const int c = o0 + ctl * 16 + l15;
            bf16x8 xf;
            if (quad < 3) {   // n = quad*8..quad*8+7 all < 25
                f32x4 u = *(const f32x4*)&xs[c * XSTR + quad * 8];
                f32x4 w = *(const f32x4*)&xs[c * XSTR + quad * 8 + 4];
                xf[0]=(__bf16)u[0]; xf[1]=(__bf16)u[1]; xf[2]=(__bf16)u[2]; xf[3]=(__bf16)u[3];
                xf[4]=(__bf16)w[0]; xf[5]=(__bf16)w[1]; xf[6]=(__bf16)w[2]; xf[7]=(__bf16)w[3];
            } else {          // n = 24..31: only 24 valid (adj k>=25 is 0 too)
                float u = xs[c * XSTR + 24];
                xf[0] = (__bf16)u;
                #pragma unroll
                for (int j = 1; j < 8; ++j) xf[j] = (__bf16)0.f;
            }
            f32x4 y0 = __builtin_amdgcn_mfma_f32_16x16x32_bf16(a0, xf, (f32x4)0.f, 0, 0, 0);
            f32x4 y1 = __builtin_amdgcn_mfma_f32_16x16x32_bf16(a1, xf, (f32x4)0.f, 0, 0, 0);
            #pragma unroll
            for (int r2 = 0; r2 < 4; ++r2) {
                ys[(quad * 4 + r2) * YSTR + c]      = (__bf16)y0[r2];
                ys[(16 + quad * 4 + r2) * YSTR + c] = (__bf16)y1[r2];
            }
        }
        // B2: ys ready. LDS drain only -- prefetch loads stay in flight.
        asm volatile("s_waitcnt lgkmcnt(0)\n\ts_barrier" ::: "memory");

        // ---- main GEMM: out[o][m] += W[o][c]*y[c][m]; af pinned in regs ----
        f32x4 acc[2][2];
        #pragma unroll
        for (int ot = 0; ot < 2; ++ot) { acc[ot][0] = (f32x4)0.f; acc[ot][1] = (f32x4)0.f; }
        #pragma unroll
        for (int kk = 0; kk < 8; ++kk) {
            bf16x8 bfr0 = *(const bf16x8*)&ys[l15 * YSTR + kk * 32 + quad * 8];
            bf16x8 bfr1 = *(const bf16x8*)&ys[(16 + l15) * YSTR + kk * 32 + quad * 8];
            #pragma unroll
            for (int ot = 0; ot < 2; ++ot) {
                acc[ot][0] = __builtin_amdgcn_mfma_f32_16x16x32_bf16(af[kk][ot], bfr0, acc[ot][0], 0, 0, 0);
                acc[ot][1] = __builtin_amdgcn_mfma_f32_16x16x32_bf16(af[kk][ot], bfr1, acc[ot][1], 0, 0, 0);
            }
        }

        // ---- epilogue: residual from xs (own rows), stage into own outS slice ----
        #pragma unroll
        for (int ot = 0; ot < 2; ++ot)
            #pragma unroll
            for (int r2 = 0; r2 < 4; ++r2) {
                const int o = o0 + ot * 16 + quad * 4 + r2;
                const float bia = biasS[o];
                {   // m = l15 (<16, always valid)
                    const int m = l15;
                    float v = acc[ot][0][r2] + bia * aS0 + xs[o * XSTR + m];
                    outS[o * N + m] = v > 0.f ? v : 0.f;
                }
                if (l15 < N - 16) {   // m = 16+l15 < 25
                    const int m = 16 + l15;
                    float v = acc[ot][1][r2] + bia * aS1 + xs[o * XSTR + m];
                    outS[o * N + m] = v > 0.f ? v : 0.f;
                }
            }

        // ---- scatter next batch into own xs rows (after residual reads; same-wave) ----
        if (pf) {
            #pragma unroll
            for (int rr = 0; rr < 4; ++rr)
                if (rr < 3 || lane < 8) {
                    int e = (wv * 200 + rr * 64 + lane) * 4;
                    int c = e / N, n = e - c * N;
                    float fv[4] = {rn[rr].x, rn[rr].y, rn[rr].z, rn[rr].w};
                    #pragma unroll
                    for (int j = 0; j < 4; ++j) {
                        xs[c * XSTR + n] = fv[j];
                        ++n; if (n == N) { n = 0; ++c; }
                    }
                }
        }

        // ---- store own outS slice, coalesced dwordx4 (same-wave data, no barrier) ----
        #pragma unroll
        for (int rr = 0; rr < 4; ++rr)
            if (rr < 3 || lane < 8) {
                int i4 = wv * 200 + rr * 64 + lane;
                ((float4*)outb)[i4] = ((const float4*)outS)[i4];
            }

        // B_end: ys free for next agg (gemm reads already consumed by MFMA deps).
        asm volatile("s_barrier" ::: "memory");
    }
}

extern "C" void kernel_launch(void* const* d_in, const int* in_sizes, int n_in,
                              void* d_out, int out_size, void* d_ws, size_t ws_size,
                              hipStream_t stream) {
    (void)in_sizes; (void)n_in; (void)out_size; (void)ws_size;
    const float* x    = (const float*)d_in[0];   // [4096, 256, 25]
    const float* adj  = (const float*)d_in[1];   // [25, 25]
    const float* W    = (const float*)d_in[2];   // [256, 256]
    const float* bias = (const float*)d_in[3];   // [256]
    float* out = (float*)d_out;

    unsigned char* ws = (unsigned char*)d_ws;
    bf16x8* Wshuf = (bf16x8*)ws;                 // 131072 B
    float*  adjS  = (float*)(ws + 131072);       // 128 B

    prep_kernel<<<32, 256, 0, stream>>>(W, adj, Wshuf, adjS);
    gcn_kernel<<<BATCH / NB, 512, 0, stream>>>(x, adj, bias, adjS, Wshuf, out);
}

// Round 2
// 204.537 us; speedup vs baseline: 1.2156x; 1.2156x over previous
//
#include <hip/hip_runtime.h>
#include <hip/hip_bf16.h>

// GraphConvolution: out = relu( (W@x + b) @ adj^T + x ), B=4096, C=256, N=25.
// R7: kill the scratch spill + LLC thrash found in R6 (FETCH 59->127MB,
// WRITE 107->140MB = 16B/thread/iter spill of the register prefetch).
//  - x prefetch now via global_load_lds (width 16) into a DOUBLE-BUFFERED
//    LINEAR fp32 x tile (rows of 25 floats, c-major == HBM order): zero
//    VGPR cost, zero scatter VALU, load window = one full iteration.
//  - counted s_waitcnt vmcnt(8/4): cur-buffer loads are always the OLDEST
//    outstanding vmem ops; stores + next-buffer loads stay in flight.
//    No vmcnt(0) anywhere in the loop.
//  - outS aliases ys (dead after GEMM ds_reads) so the 80KB/2-block LDS
//    budget holds: 51200(xs2) + 25600(ys|outS) + 2560(adj) + 1024(bias)
//    = 80384 B. One extra non-draining barrier covers the alias.
//  - xs/outS remain wave-private (own 32 c-rows); only ys crosses waves.

#define BATCH 4096
#define C 256
#define N 25
#define NB 8
#define XW 6400      // floats per batch tile (256*25), linear layout
#define YSTR 264     // ys bf16 row stride (528 B, 16B-aligned rows)

typedef __bf16 bf16x8 __attribute__((ext_vector_type(8)));
typedef float f32x4 __attribute__((ext_vector_type(4)));

#define GLOAD16(gp, lp)                                                        \
    __builtin_amdgcn_global_load_lds(                                          \
        (const __attribute__((address_space(1))) unsigned int*)(gp),           \
        (__attribute__((address_space(3))) unsigned int*)(lp), 16, 0, 0)

// ---- prep: Wshuf[(T*8+kk)*64+lane] = MFMA A-fragment, o-tile T (o=T*16+l15) ----
__global__ void prep_kernel(const float* __restrict__ W, const float* __restrict__ adj,
                            bf16x8* __restrict__ Wshuf, float* __restrict__ adjS) {
    int i = blockIdx.x * 256 + threadIdx.x;       // 8192 = 128 frags x 64 lanes
    int f = i >> 6, l = i & 63;
    int T = f >> 3, kk = f & 7;
    int quad = l >> 4, l15 = l & 15;
    int o = T * 16 + l15;
    int cb = kk * 32 + quad * 8;
    bf16x8 v;
    #pragma unroll
    for (int j = 0; j < 8; ++j) v[j] = (__bf16)W[o * C + cb + j];
    Wshuf[i] = v;
    if (blockIdx.x == 0 && threadIdx.x < 32) {
        float s = 0.f;
        if (threadIdx.x < N)
            for (int n = 0; n < N; ++n) s += adj[threadIdx.x * N + n];
        adjS[threadIdx.x] = s;
    }
}

__global__ __launch_bounds__(512, 4) void gcn_kernel(
    const float* __restrict__ x, const float* __restrict__ adj,
    const float* __restrict__ bias, const float* __restrict__ adjSg,
    const bf16x8* __restrict__ Wshuf, float* __restrict__ out)
{
    __shared__ __align__(16) float  xs2[2][XW];     // 51200 B, linear x tiles
    __shared__ __align__(16) float  outS[XW];       // 25600 B; ys aliases this
    __shared__ __align__(16) __bf16 adjbf[32 * 40]; //  2560 B zero-padded adj
    __shared__ float biasS[C];                      //  1024 B  (total 80384 B)
    __bf16* const ys = (__bf16*)outS;               // 32*264*2 = 16896 B <= 25600

    const int tid = threadIdx.x;                   // 0..511
    const int wv = tid >> 6, lane = tid & 63;      // 8 waves
    const int quad = lane >> 4, l15 = lane & 15;
    const int o0 = wv * 32;                        // wave's o-range == c-range
    const int b0 = blockIdx.x * NB;

    // ---- one-time: adj staging, bias, pinned W fragments (64 VGPRs) ----
    for (int e = tid; e < N * N; e += 512) {
        int m = e / N, n = e - m * N;
        adjbf[m * 40 + n] = (__bf16)adj[e];
    }
    if (tid < N) {
        #pragma unroll
        for (int n = N; n < 32; ++n) adjbf[tid * 40 + n] = (__bf16)0.f;
    } else if (tid < 32) {
        #pragma unroll
        for (int n = 0; n < 32; ++n) adjbf[tid * 40 + n] = (__bf16)0.f;
    }
    if (tid < C) biasS[tid] = bias[tid];

    bf16x8 af[8][2];   // 64 VGPRs, coalesced 1KB loads
    #pragma unroll
    for (int kk = 0; kk < 8; ++kk)
        #pragma unroll
        for (int ot = 0; ot < 2; ++ot)
            af[kk][ot] = Wshuf[(((wv * 2 + ot) * 8 + kk) << 6) + lane];

    const float aS0 = adjSg[l15];
    const float aS1 = adjSg[16 + l15];

    __syncthreads();   // adjbf/biasS ready; drains all one-time vmem too

    const bf16x8 a0 = *(const bf16x8*)&adjbf[l15 * 40 + quad * 8];
    const bf16x8 a1 = *(const bf16x8*)&adjbf[(16 + l15) * 40 + quad * 8];

    // ---- prologue: async-stage batch b0 into xs2[0] (own 32 rows = 3200 B) ----
    {
        const float4* xb = (const float4*)(x + (size_t)b0 * XW);
        #pragma unroll
        for (int rr = 0; rr < 4; ++rr)
            if (rr < 3 || lane < 8)
                GLOAD16(xb + (wv * 200 + rr * 64 + lane),
                        &xs2[0][(wv * 200 + rr * 64) * 4]);
    }

    #pragma unroll 1
    for (int bi = 0; bi < NB; ++bi) {
        const int cur = bi & 1;
        float* outb = out + (size_t)(b0 + bi) * XW;
        const bool pf = (bi + 1 < NB);

        // ---- issue next-batch loads into the other buffer (dead since bi-1) ----
        if (pf) {
            const float4* xb = (const float4*)(x + (size_t)(b0 + bi + 1) * XW);
            #pragma unroll
            for (int rr = 0; rr < 4; ++rr)
                if (rr < 3 || lane < 8)
                    GLOAD16(xb + (wv * 200 + rr * 64 + lane),
                            &xs2[cur ^ 1][(wv * 200 + rr * 64) * 4]);
        }

        // ---- wait for OWN buf[cur] loads (oldest outstanding); keep stores +
        //      new loads in flight. Queue: [cur loads(4), stores(4, bi>0), new(4, pf)]
        if (bi == 0 || !pf) asm volatile("s_waitcnt vmcnt(4)" ::: "memory");
        else                asm volatile("s_waitcnt vmcnt(8)" ::: "memory");

        const float* xc = xs2[cur];

        // ---- agg MFMA on own rows: y[m][c]=sum_n adj[m][n]*x[c][n] ----
        #pragma unroll
        for (int ctl = 0; ctl < 2; ++ctl) {
            const int c = o0 + ctl * 16 + l15;
            const float* xr = xc + c * N;
            bf16x8 xf;
            if (quad < 3) {   // n = quad*8..quad*8+7 all < 25
                #pragma unroll
                for (int j = 0; j < 8; ++j) xf[j] = (__bf16)xr[quad * 8 + j];
            } else {          // n = 24..31: only 24 valid (adj k>=25 is 0 too)
                xf[0] = (__bf16)xr[24];
                #pragma unroll
                for (int j = 1; j < 8; ++j) xf[j] = (__bf16)0.f;
            }
            f32x4 y0 = __builtin_amdgcn_mfma_f32_16x16x32_bf16(a0, xf, (f32x4)0.f, 0, 0, 0);
            f32x4 y1 = __builtin_amdgcn_mfma_f32_16x16x32_bf16(a1, xf, (f32x4)0.f, 0, 0, 0);
            #pragma unroll
            for (int r2 = 0; r2 < 4; ++r2) {
                ys[(quad * 4 + r2) * YSTR + c]      = (__bf16)y0[r2];
                ys[(16 + quad * 4 + r2) * YSTR + c] = (__bf16)y1[r2];
            }
        }
        // B1: ys ready (LDS drain only; vmem stays in flight)
        asm volatile("s_waitcnt lgkmcnt(0)\n\ts_barrier" ::: "memory");

        // ---- main GEMM: out[o][m] += W[o][c]*y[c][m]; af pinned in regs ----
        f32x4 acc[2][2];
        #pragma unroll
        for (int ot = 0; ot < 2; ++ot) { acc[ot][0] = (f32x4)0.f; acc[ot][1] = (f32x4)0.f; }
        #pragma unroll
        for (int kk = 0; kk < 8; ++kk) {
            bf16x8 bfr0 = *(const bf16x8*)&ys[l15 * YSTR + kk * 32 + quad * 8];
            bf16x8 bfr1 = *(const bf16x8*)&ys[(16 + l15) * YSTR + kk * 32 + quad * 8];
            #pragma unroll
            for (int ot = 0; ot < 2; ++ot) {
                acc[ot][0] = __builtin_amdgcn_mfma_f32_16x16x32_bf16(af[kk][ot], bfr0, acc[ot][0], 0, 0, 0);
                acc[ot][1] = __builtin_amdgcn_mfma_f32_16x16x32_bf16(af[kk][ot], bfr1, acc[ot][1], 0, 0, 0);
            }
        }
        // B2: all waves done reading ys -> safe to overwrite as outS.
        // (this wave's ds_reads were consumed by MFMA data-deps already)
        asm volatile("s_barrier" ::: "memory");

        // ---- epilogue: residual from xs (own rows), stage into own outS slice ----
        #pragma unroll
        for (int ot = 0; ot < 2; ++ot)
            #pragma unroll
            for (int r2 = 0; r2 < 4; ++r2) {
                const int o = o0 + ot * 16 + quad * 4 + r2;
                const float bia = biasS[o];
                {   // m = l15 (<16, always valid)
                    const int m = l15;
                    float v = acc[ot][0][r2] + bia * aS0 + xc[o * N + m];
                    outS[o * N + m] = v > 0.f ? v : 0.f;
                }
                if (l15 < N - 16) {   // m = 16+l15 < 25
                    const int m = 16 + l15;
                    float v = acc[ot][1][r2] + bia * aS1 + xc[o * N + m];
                    outS[o * N + m] = v > 0.f ? v : 0.f;
                }
            }

        // ---- store own outS slice, coalesced dwordx4 (wave-private, no barrier) ----
        #pragma unroll
        for (int rr = 0; rr < 4; ++rr)
            if (rr < 3 || lane < 8) {
                int i4 = wv * 200 + rr * 64 + lane;
                ((float4*)outb)[i4] = ((const float4*)outS)[i4];
            }

        // B3: outS ds_reads done (consumed before store issue) -> next ys writes safe.
        asm volatile("s_barrier" ::: "memory");
    }
}

extern "C" void kernel_launch(void* const* d_in, const int* in_sizes, int n_in,
                              void* d_out, int out_size, void* d_ws, size_t ws_size,
                              hipStream_t stream) {
    (void)in_sizes; (void)n_in; (void)out_size; (void)ws_size;
    const float* x    = (const float*)d_in[0];   // [4096, 256, 25]
    const float* adj  = (const float*)d_in[1];   // [25, 25]
    const float* W    = (const float*)d_in[2];   // [256, 256]
    const float* bias = (const float*)d_in[3];   // [256]
    float* out = (float*)d_out;

    unsigned char* ws = (unsigned char*)d_ws;
    bf16x8* Wshuf = (bf16x8*)ws;                 // 131072 B
    float*  adjS  = (float*)(ws + 131072);       // 128 B

    prep_kernel<<<32, 256, 0, stream>>>(W, adj, Wshuf, adjS);
    gcn_kernel<<<BATCH / NB, 512, 0, stream>>>(x, adj, bias, adjS, Wshuf, out);
}